// Round 14
// baseline (723.073 us; speedup 1.0000x reference)
//
#include <hip/hip_runtime.h>

#define NB 2
#define NN 4096
#define DIMD 512
#define PD 64
#define KNN 16
#define QB 4
#define CAP 192
#define CTRIG 52
#define RCAP 48
#define MROWS (NB*NN)       // 8192
#define FLOW_BLOCKS (MROWS/4)

typedef unsigned short ushort_t;

// ---------------- kernel 1: fused prep = flow (f64) + values GEMM (grid-split) -------------
__global__ __launch_bounds__(256)
void prep_kernel(const float* __restrict__ states, const float* __restrict__ positions,
                 const float* __restrict__ W_flow, const float* __restrict__ b_flow,
                 const float* __restrict__ W_val, const float* __restrict__ b_val,
                 float* __restrict__ out_np, float* __restrict__ out_fl,
                 float* __restrict__ npos_lo, float* __restrict__ p4t,
                 double* __restrict__ sq64, float* __restrict__ sqf,
                 float* __restrict__ values_ws)
{
    __shared__ float s_lds[4][DIMD];
    __shared__ float As[16][68];
    __shared__ float Bs[16][68];
    const int t = threadIdx.x;

    if (blockIdx.x < FLOW_BLOCKS) {
        const int row0 = blockIdx.x * 4;
        const float4* src = (const float4*)(states + (size_t)row0 * DIMD);
        float4* dst = (float4*)&s_lds[0][0];
        dst[t] = src[t];
        dst[t + 256] = src[t + 256];
        __syncthreads();
        const int lr = t >> 6;
        const int p  = t & 63;
        const int row = row0 + lr;
        const float4* wr = (const float4*)(W_flow + (size_t)p * DIMD);
        const float4* sr = (const float4*)&s_lds[lr][0];
        double acc = 0.0;
        #pragma unroll 8
        for (int d4 = 0; d4 < DIMD/4; ++d4) {
            float4 w4 = wr[d4];
            float4 s4 = sr[d4];
            acc += (double)s4.x * (double)w4.x;
            acc += (double)s4.y * (double)w4.y;
            acc += (double)s4.z * (double)w4.z;
            acc += (double)s4.w * (double)w4.w;
        }
        acc += (double)b_flow[p];
        const size_t g = (size_t)row * PD + p;
        double np_ = (double)positions[g] + 0.1 * acc;
        float hi = (float)np_;
        float lo = (float)(np_ - (double)hi);
        out_fl[g]   = (float)acc;
        out_np[g]   = hi;
        npos_lo[g]  = lo;
        const int bb = row >> 12, n = row & (NN - 1);
        p4t[(((size_t)bb*16 + (p >> 2))*NN + n)*4 + (p & 3)] = hi;
        double s2 = np_ * np_;
        #pragma unroll
        for (int off = 32; off >= 1; off >>= 1) s2 += __shfl_xor(s2, off);
        if (p == 0) { sq64[row] = s2; sqf[row] = (float)s2; }
    } else {
        const int idx = blockIdx.x - FLOW_BLOCKS;
        const int bn = idx & 7, bm = idx >> 3;
        const int lr  = t >> 2;
        const int lc4 = (t & 3) << 2;
        const int cr = (t >> 4) << 2;
        const int cc = (t & 15) << 2;
        float acc[4][4] = {};
        for (int k0 = 0; k0 < DIMD; k0 += 16) {
            float4 av = *(const float4*)(states + (size_t)(bm*64 + lr)*DIMD + k0 + lc4);
            float4 wv = *(const float4*)(W_val  + (size_t)(bn*64 + lr)*DIMD + k0 + lc4);
            __syncthreads();
            As[lc4+0][lr] = av.x; As[lc4+1][lr] = av.y; As[lc4+2][lr] = av.z; As[lc4+3][lr] = av.w;
            Bs[lc4+0][lr] = wv.x; Bs[lc4+1][lr] = wv.y; Bs[lc4+2][lr] = wv.z; Bs[lc4+3][lr] = wv.w;
            __syncthreads();
            #pragma unroll
            for (int kk = 0; kk < 16; ++kk) {
                float4 a  = *(const float4*)&As[kk][cr];
                float4 b4 = *(const float4*)&Bs[kk][cc];
                acc[0][0] += a.x*b4.x; acc[0][1] += a.x*b4.y; acc[0][2] += a.x*b4.z; acc[0][3] += a.x*b4.w;
                acc[1][0] += a.y*b4.x; acc[1][1] += a.y*b4.y; acc[1][2] += a.y*b4.z; acc[1][3] += a.y*b4.w;
                acc[2][0] += a.z*b4.x; acc[2][1] += a.z*b4.y; acc[2][2] += a.z*b4.z; acc[2][3] += a.z*b4.w;
                acc[3][0] += a.w*b4.x; acc[3][1] += a.w*b4.y; acc[3][2] += a.w*b4.z; acc[3][3] += a.w*b4.w;
            }
        }
        const int colb = bn*64 + cc;
        float4 bb = *(const float4*)(b_val + colb);
        #pragma unroll
        for (int i = 0; i < 4; ++i) {
            float4 o;
            o.x = acc[i][0] + bb.x;
            o.y = acc[i][1] + bb.y;
            o.z = acc[i][2] + bb.z;
            o.w = acc[i][3] + bb.w;
            *(float4*)(values_ws + (size_t)(bm*64 + cr + i)*DIMD + colb) = o;
        }
    }
}

// ---------------- kernel 2: 4q/block dedup scan (r6 selection) + f64 rescue + context ------
// 2048 blocks -> 8 blocks/CU (32-wave cap). 256 thr = 4 waves; wave w owns candidate
// quarter w (1024) for ALL 4 queries. Selection = r6/r11/r12's proven scheme verbatim:
// bf16-trunc entries, 16-iter searches, CTRIG 52 (compacts rare), CAP 192 >= 52+128
// deterministic no-overflow. ONLY change vs r12 (passed): launch_bounds min-waves 6 -> 4
// so the register allocator is not strangled (r12's (256,6) forced VGPR=40 -> scratch
// spill, 1.9 GB FETCH). Expect VGPR ~56-72, no spill.
__global__ __launch_bounds__(256, 4)
void dist_kernel(const float* __restrict__ nph, const float* __restrict__ npl,
                 const float4* __restrict__ p4t, const float* __restrict__ sqf,
                 const double* __restrict__ sq64, const float* __restrict__ values,
                 float* __restrict__ ctx)
{
    __shared__ __align__(16) unsigned char POOL[12288];
    __shared__ float    qstage[QB][68];
    __shared__ ushort_t rlist[QB][4][RCAP];
    __shared__ int      ccnt[QB][4];
    __shared__ int      rcnt[QB][4];

    // phase 1 aliases
    ushort_t (*sd16)[4][CAP]  = (ushort_t(*)[4][CAP])POOL;               // 6144
    ushort_t (*six16)[4][CAP] = (ushort_t(*)[4][CAP])(POOL + 6144);      // 6144
    // phase 2 aliases
    double (*umbd)[192] = (double(*)[192])POOL;                          // 6144
    int*    umbi        = (int*)(POOL + 6144);                           // 3072
    double (*qd64)[66]  = (double(*)[66])(POOL + 9216);                  // 2112
    int*    fin_ix      = (int*)(POOL + 11328);                          //  256
    float*  fin_w       = (float*)(POOL + 11584);                        //  256

    const int tid  = threadIdx.x;
    const int w    = tid >> 6;        // quarter id
    const int lane = tid & 63;
    const int b    = blockIdx.x >> 10;
    const int n0   = (blockIdx.x & 1023) << 2;
    const int base = b * NN;

    if (tid < 16) ccnt[tid >> 2][tid & 3] = 0;
    if (tid < 64) {
        int row = tid >> 4, c4 = (tid & 15) << 2;
        *(float4*)&qstage[row][c4] = *(const float4*)(nph + (size_t)(base + n0 + row)*PD + c4);
    }
    __syncthreads();

    float sqq[QB], tv[QB];
    #pragma unroll
    for (int j = 0; j < QB; ++j) { sqq[j] = sqf[base + n0 + j]; tv[j] = 1e30f; }

    const float4* P4 = p4t + (size_t)b * 16 * NN;
    const int qbase = w << 10;

    // ---- scan: 8 chunks of 128 cands per quarter (r6/r11 shape) ----
    for (int ch = 0; ch < 8; ++ch) {
        const int cbase = qbase + (ch << 7);
        const int c0 = cbase + lane, c1 = c0 + 64;
        float a[QB][2];
        #pragma unroll
        for (int j = 0; j < QB; ++j) { a[j][0] = 0.f; a[j][1] = 0.f; }
        #pragma unroll
        for (int k4 = 0; k4 < 16; ++k4) {
            float4 p0 = P4[(size_t)k4*NN + c0];
            float4 p1 = P4[(size_t)k4*NN + c1];
            #pragma unroll
            for (int j = 0; j < QB; ++j) {
                float4 qv = *(const float4*)&qstage[j][k4 << 2];
                a[j][0] += qv.x*p0.x + qv.y*p0.y + qv.z*p0.z + qv.w*p0.w;
                a[j][1] += qv.x*p1.x + qv.y*p1.y + qv.z*p1.z + qv.w*p1.w;
            }
        }
        const float sc0 = sqf[base + c0], sc1 = sqf[base + c1];
        #pragma unroll
        for (int j = 0; j < QB; ++j) {
            float d0 = fmaxf(sqq[j] + sc0 - 2.f*a[j][0], 0.f);
            float d1 = fmaxf(sqq[j] + sc1 - 2.f*a[j][1], 0.f);
            if (c0 == n0 + j) d0 = 1e30f;   // self
            if (c1 == n0 + j) d1 = 1e30f;
            a[j][0] = d0; a[j][1] = d1;
        }

        if (ch == 0) {
            // t0: smallest bf16 boundary with >=19 of this chunk's 128 d2 strictly below
            #pragma unroll
            for (int j = 0; j < QB; ++j) {
                unsigned lo = 0u, hi = 0x7F80u;
                #pragma unroll 1
                for (int it = 0; it < 16; ++it) {
                    unsigned mid = (lo + hi) >> 1;
                    float fm = __uint_as_float(mid << 16);
                    int cnt = __popcll(__ballot(a[j][0] < fm)) + __popcll(__ballot(a[j][1] < fm));
                    if (cnt >= 19) hi = mid; else lo = mid;
                }
                tv[j] = __uint_as_float(hi << 16);
            }
        }

        // append passers (deterministically within CAP)
        #pragma unroll
        for (int j = 0; j < QB; ++j) {
            if (a[j][0] < tv[j]) {
                int s = atomicAdd(&ccnt[j][w], 1);
                if (s < CAP) {
                    sd16[j][w][s]  = (ushort_t)(__float_as_uint(a[j][0]) >> 16);
                    six16[j][w][s] = (ushort_t)c0;
                }
            }
            if (a[j][1] < tv[j]) {
                int s = atomicAdd(&ccnt[j][w], 1);
                if (s < CAP) {
                    sd16[j][w][s]  = (ushort_t)(__float_as_uint(a[j][1]) >> 16);
                    six16[j][w][s] = (ushort_t)c1;
                }
            }
        }

        // deterministic compact (rare; wave-uniform branch): keep bf16-top-~19, tighten tv
        #pragma unroll
        for (int j = 0; j < QB; ++j) {
            int cnt0 = ccnt[j][w];
            if (cnt0 > CTRIG) {
                if (cnt0 > CAP) cnt0 = CAP;
                ushort_t v0 = (lane       < cnt0) ? sd16[j][w][lane]       : (ushort_t)0xFFFF;
                ushort_t v1 = (64 + lane  < cnt0) ? sd16[j][w][64 + lane]  : (ushort_t)0xFFFF;
                ushort_t v2 = (128 + lane < cnt0) ? sd16[j][w][128 + lane] : (ushort_t)0xFFFF;
                ushort_t i0 = (lane       < cnt0) ? six16[j][w][lane]       : (ushort_t)0;
                ushort_t i1 = (64 + lane  < cnt0) ? six16[j][w][64 + lane]  : (ushort_t)0;
                ushort_t i2 = (128 + lane < cnt0) ? six16[j][w][128 + lane] : (ushort_t)0;
                unsigned lo = 0u, hi = 0x7F80u;
                #pragma unroll 1
                for (int it = 0; it < 16; ++it) {
                    unsigned mid = (lo + hi) >> 1;
                    int cnt = __popcll(__ballot((unsigned)v0 < mid))
                            + __popcll(__ballot((unsigned)v1 < mid))
                            + __popcll(__ballot((unsigned)v2 < mid));
                    if (cnt >= 19) hi = mid; else lo = mid;
                }
                tv[j] = __uint_as_float(hi << 16);
                if (lane == 0) ccnt[j][w] = 0;
                if ((unsigned)v0 < hi) { int s = atomicAdd(&ccnt[j][w], 1); sd16[j][w][s] = v0; six16[j][w][s] = i0; }
                if ((unsigned)v1 < hi) { int s = atomicAdd(&ccnt[j][w], 1); sd16[j][w][s] = v1; six16[j][w][s] = i1; }
                if ((unsigned)v2 < hi) { int s = atomicAdd(&ccnt[j][w], 1); sd16[j][w][s] = v2; six16[j][w][s] = i2; }
            }
        }
    }

    // ---- final compact to rescue list (bf16 20-quantile, keep < t) ----
    if (lane < QB) rcnt[lane][w] = 0;
    #pragma unroll 1
    for (int j = 0; j < QB; ++j) {
        int cnt0 = ccnt[j][w];
        if (cnt0 > CAP) cnt0 = CAP;
        ushort_t v0 = (lane       < cnt0) ? sd16[j][w][lane]       : (ushort_t)0xFFFF;
        ushort_t v1 = (64 + lane  < cnt0) ? sd16[j][w][64 + lane]  : (ushort_t)0xFFFF;
        ushort_t v2 = (128 + lane < cnt0) ? sd16[j][w][128 + lane] : (ushort_t)0xFFFF;
        ushort_t i0 = (lane       < cnt0) ? six16[j][w][lane]       : (ushort_t)0;
        ushort_t i1 = (64 + lane  < cnt0) ? six16[j][w][64 + lane]  : (ushort_t)0;
        ushort_t i2 = (128 + lane < cnt0) ? six16[j][w][128 + lane] : (ushort_t)0;
        unsigned lo = 0u, hi = 0x7F80u;
        #pragma unroll 1
        for (int it = 0; it < 16; ++it) {
            unsigned mid = (lo + hi) >> 1;
            int cnt = __popcll(__ballot((unsigned)v0 < mid))
                    + __popcll(__ballot((unsigned)v1 < mid))
                    + __popcll(__ballot((unsigned)v2 < mid));
            if (cnt >= 20) hi = mid; else lo = mid;
        }
        if ((unsigned)v0 < hi) { int s = atomicAdd(&rcnt[j][w], 1); if (s < RCAP) rlist[j][w][s] = i0; }
        if ((unsigned)v1 < hi) { int s = atomicAdd(&rcnt[j][w], 1); if (s < RCAP) rlist[j][w][s] = i1; }
        if ((unsigned)v2 < hi) { int s = atomicAdd(&rcnt[j][w], 1); if (s < RCAP) rlist[j][w][s] = i2; }
    }
    __syncthreads();   // sd16/six16 dead -> repurpose POOL

    // ---- build qd64 (f64 query rows) + init umb ----
    for (int i = tid; i < QB*PD; i += 256) {
        int q = i >> 6, p = i & 63;
        size_t g = (size_t)(base + n0 + q)*PD + p;
        qd64[q][p] = (double)nph[g] + (double)npl[g];
    }
    for (int i = tid; i < QB*192; i += 256) {
        umbd[i / 192][i % 192] = 1e300;
        umbi[i] = 0x7fffffff;
    }
    __syncthreads();

    // ---- coalesced f64 rescue: 16-lane groups, 4 candidates per iteration ----
    const int lh = lane & 15, g4 = lane >> 4;
    #pragma unroll 1
    for (int q = 0; q < QB; ++q) {
        int cr = rcnt[q][w]; if (cr > RCAP) cr = RCAP;
        const double qd0 = qd64[q][4*lh+0], qd1 = qd64[q][4*lh+1];
        const double qd2 = qd64[q][4*lh+2], qd3 = qd64[q][4*lh+3];
        const double sq_q = sq64[base + n0 + q];
        for (int s0 = 0; s0 < cr; s0 += 4) {
            const int slot = s0 + g4;
            const bool valid = slot < cr;
            const int cand = valid ? (int)rlist[q][w][slot] : 0;
            const float4 h4 = *(const float4*)(nph + (size_t)(base + cand)*PD + 4*lh);
            const float4 l4 = *(const float4*)(npl + (size_t)(base + cand)*PD + 4*lh);
            double acc = qd0*((double)h4.x + (double)l4.x)
                       + qd1*((double)h4.y + (double)l4.y)
                       + qd2*((double)h4.z + (double)l4.z)
                       + qd3*((double)h4.w + (double)l4.w);
            #pragma unroll
            for (int off = 1; off < 16; off <<= 1) acc += __shfl_xor(acc, off);
            if (valid && lh == 0) {
                umbd[q][w*RCAP + slot] = sq_q + sq64[base + cand] - 2.0*acc;
                umbi[q*192 + w*RCAP + slot] = cand;
            }
        }
    }
    __syncthreads();

    // ---- exact f64 top-16 + weights: wave w -> query w (union <= 192) ----
    {
        const int q = w;
        double ev0 = umbd[q][lane], ev1 = umbd[q][64 + lane], ev2 = umbd[q][128 + lane];
        int ei0 = umbi[q*192 + lane], ei1 = umbi[q*192 + 64 + lane], ei2 = umbi[q*192 + 128 + lane];
        double wsum = 0.0, mywk = 0.0;
        for (int r = 0; r < KNN; ++r) {
            double bv = ev0; int bi = ei0; int bs = 0;
            if (ev1 < bv || (ev1 == bv && ei1 < bi)) { bv = ev1; bi = ei1; bs = 1; }
            if (ev2 < bv || (ev2 == bv && ei2 < bi)) { bv = ev2; bi = ei2; bs = 2; }
            #pragma unroll
            for (int off = 32; off >= 1; off >>= 1) {
                double ov = __shfl_xor(bv, off);
                int    oi = __shfl_xor(bi, off);
                if (ov < bv || (ov == bv && oi < bi)) { bv = ov; bi = oi; }
            }
            if (bs == 0 && ei0 == bi) ev0 = 1e300;
            if (bs == 1 && ei1 == bi) ev1 = 1e300;
            if (bs == 2 && ei2 == bi) ev2 = 1e300;
            double wk = exp(-0.5 * sqrt(fmax(bv, 1e-12)));
            wsum += wk;
            if (lane == r) mywk = wk;
            if (lane == 0) fin_ix[q*16 + r] = bi;
        }
        if (lane < KNN) fin_w[q*16 + lane] = (float)(mywk / (wsum + 1e-8));
    }
    __syncthreads();

    // ---- context: 4 queries x 512 dims (64 thr/query, 8 dims each) ----
    {
        const int q  = tid >> 6;
        const int e0 = (tid & 63) << 3;
        const float* V = values + (size_t)base * DIMD;
        float acc2[8] = {};
        for (int k = 0; k < KNN; ++k) {
            int   m  = fin_ix[q*16 + k];
            float wg = fin_w[q*16 + k];
            const float4* vr = (const float4*)(V + (size_t)m*DIMD + e0);
            #pragma unroll
            for (int t4 = 0; t4 < 2; ++t4) {
                float4 vv = vr[t4];
                acc2[4*t4+0] += wg*vv.x; acc2[4*t4+1] += wg*vv.y;
                acc2[4*t4+2] += wg*vv.z; acc2[4*t4+3] += wg*vv.w;
            }
        }
        float* crow = ctx + (size_t)(base + n0 + q)*DIMD + e0;
        #pragma unroll
        for (int t4 = 0; t4 < 2; ++t4)
            *(float4*)(crow + 4*t4) = make_float4(acc2[4*t4+0], acc2[4*t4+1], acc2[4*t4+2], acc2[4*t4+3]);
    }
}

extern "C" void kernel_launch(void* const* d_in, const int* in_sizes, int n_in,
                              void* d_out, int out_size, void* d_ws, size_t ws_size,
                              hipStream_t stream)
{
    (void)in_sizes; (void)n_in; (void)out_size; (void)ws_size;
    const float* states    = (const float*)d_in[0];
    const float* positions = (const float*)d_in[1];
    const float* W_flow    = (const float*)d_in[2];
    const float* b_flow    = (const float*)d_in[3];
    const float* W_val     = (const float*)d_in[4];
    const float* b_val     = (const float*)d_in[5];

    float* out_ctx = (float*)d_out;                       // [B,N,DIM]
    float* out_np  = out_ctx + (size_t)NB*NN*DIMD;        // [B,N,PD]
    float* out_fl  = out_np  + (size_t)NB*NN*PD;          // [B,N,PD]

    char* ws = (char*)d_ws;
    float*  values_ws = (float*)ws;                                   // 16,777,216 B
    float*  npos_lo   = (float*)(ws + (size_t)16777216);              //  2,097,152 B
    double* sq64      = (double*)(ws + (size_t)18874368);             //     65,536 B
    float*  sqf       = (float*)(ws + (size_t)18939904);              //     32,768 B
    float*  p4t       = (float*)(ws + (size_t)18972672);              //  2,097,152 B
    // total 21,069,824 B (same footprint as rounds 3-13)

    hipLaunchKernelGGL(prep_kernel, dim3(FLOW_BLOCKS + (DIMD/64)*(MROWS/64)), dim3(256), 0, stream,
                       states, positions, W_flow, b_flow, W_val, b_val,
                       out_np, out_fl, npos_lo, p4t, sq64, sqf, values_ws);
    hipLaunchKernelGGL(dist_kernel, dim3(MROWS/QB), dim3(256), 0, stream,
                       out_np, npos_lo, (const float4*)p4t, sqf, sq64, values_ws, out_ctx);
}

// Round 15
// 456.142 us; speedup vs baseline: 1.5852x; 1.5852x over previous
//
#include <hip/hip_runtime.h>

#define NB 2
#define NN 4096
#define DIMD 512
#define PD 64
#define KNN 16
#define QB 8
#define CAP 192
#define CTRIG 52
#define RCAP 48
#define MROWS (NB*NN)       // 8192
#define FLOW_BLOCKS (MROWS/4)

typedef unsigned short ushort_t;

// ---------------- kernel 1: fused prep = flow (f64, 4-way ILP) + values GEMM ---------------
__global__ __launch_bounds__(256)
void prep_kernel(const float* __restrict__ states, const float* __restrict__ positions,
                 const float* __restrict__ W_flow, const float* __restrict__ b_flow,
                 const float* __restrict__ W_val, const float* __restrict__ b_val,
                 float* __restrict__ out_np, float* __restrict__ out_fl,
                 float* __restrict__ npos_lo, float* __restrict__ p4t,
                 double* __restrict__ sq64, float* __restrict__ sqf,
                 float* __restrict__ values_ws)
{
    __shared__ float s_lds[4][DIMD];
    __shared__ float As[16][68];
    __shared__ float Bs[16][68];
    const int t = threadIdx.x;

    if (blockIdx.x < FLOW_BLOCKS) {
        const int row0 = blockIdx.x * 4;
        const float4* src = (const float4*)(states + (size_t)row0 * DIMD);
        float4* dst = (float4*)&s_lds[0][0];
        dst[t] = src[t];
        dst[t + 256] = src[t + 256];
        __syncthreads();
        const int lr = t >> 6;
        const int p  = t & 63;
        const int row = row0 + lr;
        const float4* wr = (const float4*)(W_flow + (size_t)p * DIMD);
        const float4* sr = (const float4*)&s_lds[lr][0];
        // 4 independent f64 partials (break the 512-deep dependent FMA chain)
        double a0 = 0.0, a1 = 0.0, a2 = 0.0, a3 = 0.0;
        #pragma unroll 8
        for (int d4 = 0; d4 < DIMD/4; ++d4) {
            float4 w4 = wr[d4];
            float4 s4 = sr[d4];
            a0 += (double)s4.x * (double)w4.x;
            a1 += (double)s4.y * (double)w4.y;
            a2 += (double)s4.z * (double)w4.z;
            a3 += (double)s4.w * (double)w4.w;
        }
        double acc = ((a0 + a1) + (a2 + a3)) + (double)b_flow[p];
        const size_t g = (size_t)row * PD + p;
        double np_ = (double)positions[g] + 0.1 * acc;
        float hi = (float)np_;
        float lo = (float)(np_ - (double)hi);
        out_fl[g]   = (float)acc;
        out_np[g]   = hi;
        npos_lo[g]  = lo;
        const int bb = row >> 12, n = row & (NN - 1);
        p4t[(((size_t)bb*16 + (p >> 2))*NN + n)*4 + (p & 3)] = hi;
        double s2 = np_ * np_;
        #pragma unroll
        for (int off = 32; off >= 1; off >>= 1) s2 += __shfl_xor(s2, off);
        if (p == 0) { sq64[row] = s2; sqf[row] = (float)s2; }
    } else {
        const int idx = blockIdx.x - FLOW_BLOCKS;
        const int bn = idx & 7, bm = idx >> 3;
        const int lr  = t >> 2;
        const int lc4 = (t & 3) << 2;
        const int cr = (t >> 4) << 2;
        const int cc = (t & 15) << 2;
        float acc[4][4] = {};
        for (int k0 = 0; k0 < DIMD; k0 += 16) {
            float4 av = *(const float4*)(states + (size_t)(bm*64 + lr)*DIMD + k0 + lc4);
            float4 wv = *(const float4*)(W_val  + (size_t)(bn*64 + lr)*DIMD + k0 + lc4);
            __syncthreads();
            As[lc4+0][lr] = av.x; As[lc4+1][lr] = av.y; As[lc4+2][lr] = av.z; As[lc4+3][lr] = av.w;
            Bs[lc4+0][lr] = wv.x; Bs[lc4+1][lr] = wv.y; Bs[lc4+2][lr] = wv.z; Bs[lc4+3][lr] = wv.w;
            __syncthreads();
            #pragma unroll
            for (int kk = 0; kk < 16; ++kk) {
                float4 a  = *(const float4*)&As[kk][cr];
                float4 b4 = *(const float4*)&Bs[kk][cc];
                acc[0][0] += a.x*b4.x; acc[0][1] += a.x*b4.y; acc[0][2] += a.x*b4.z; acc[0][3] += a.x*b4.w;
                acc[1][0] += a.y*b4.x; acc[1][1] += a.y*b4.y; acc[1][2] += a.y*b4.z; acc[1][3] += a.y*b4.w;
                acc[2][0] += a.z*b4.x; acc[2][1] += a.z*b4.y; acc[2][2] += a.z*b4.z; acc[2][3] += a.z*b4.w;
                acc[3][0] += a.w*b4.x; acc[3][1] += a.w*b4.y; acc[3][2] += a.w*b4.z; acc[3][3] += a.w*b4.w;
            }
        }
        const int colb = bn*64 + cc;
        float4 bb = *(const float4*)(b_val + colb);
        #pragma unroll
        for (int i = 0; i < 4; ++i) {
            float4 o;
            o.x = acc[i][0] + bb.x;
            o.y = acc[i][1] + bb.y;
            o.z = acc[i][2] + bb.z;
            o.w = acc[i][3] + bb.w;
            *(float4*)(values_ws + (size_t)(bm*64 + cr + i)*DIMD + colb) = o;
        }
    }
}

// ---------------- kernel 2: 8q/block dedup scan + f64 rescue + context (r11 base) ----------
// r11 verbatim EXCEPT: query rows are read via wave-uniform GLOBAL loads (s_load_dwordx4 on
// the SMEM/SALU pipe) instead of qstage LDS reads -> removes 128 ds_read_b128 per chunk per
// wave. Values identical (qstage was a copy of nph); selection arithmetic bit-identical.
__global__ __launch_bounds__(256, 4)
void dist_kernel(const float* __restrict__ nph, const float* __restrict__ npl,
                 const float4* __restrict__ p4t, const float* __restrict__ sqf,
                 const double* __restrict__ sq64, const float* __restrict__ values,
                 float* __restrict__ ctx)
{
    __shared__ __align__(16) unsigned char POOL[24576];
    __shared__ ushort_t rlist[QB][4][RCAP];
    __shared__ int      ccnt[QB][4];
    __shared__ int      rcnt[QB][4];

    // phase 1 aliases
    ushort_t (*sd16)[4][CAP]  = (ushort_t(*)[4][CAP])POOL;               // 12288
    ushort_t (*six16)[4][CAP] = (ushort_t(*)[4][CAP])(POOL + 12288);     // 12288
    // phase 2 aliases
    double (*umbd)[192] = (double(*)[192])POOL;                          // 12288
    int*    umbi        = (int*)(POOL + 12288);                          //  6144
    double (*qd64)[66]  = (double(*)[66])(POOL + 18432);                 //  4224
    int*    fin_ix      = (int*)(POOL + 22656);                          //   512
    float*  fin_w       = (float*)(POOL + 23168);                        //   512

    const int tid  = threadIdx.x;
    const int w    = tid >> 6;        // quarter id
    const int lane = tid & 63;
    const int b    = blockIdx.x >> 9;
    const int n0   = (blockIdx.x & 511) << 3;
    const int base = b * NN;

    if (tid < 32) ccnt[tid >> 2][tid & 3] = 0;
    __syncthreads();

    float sqq[QB], tv[QB];
    #pragma unroll
    for (int j = 0; j < QB; ++j) { sqq[j] = sqf[base + n0 + j]; tv[j] = 1e30f; }

    const float4* P4 = p4t + (size_t)b * 16 * NN;
    const float*  QR = nph + (size_t)(base + n0) * PD;   // wave-uniform rows -> s_load
    const int qbase = w << 10;

    // ---- scan: 8 chunks of 128 cands per quarter (r11 shape) ----
    for (int ch = 0; ch < 8; ++ch) {
        const int cbase = qbase + (ch << 7);
        const int c0 = cbase + lane, c1 = c0 + 64;
        float a[QB][2];
        #pragma unroll
        for (int j = 0; j < QB; ++j) { a[j][0] = 0.f; a[j][1] = 0.f; }
        #pragma unroll
        for (int k4 = 0; k4 < 16; ++k4) {
            float4 p0 = P4[(size_t)k4*NN + c0];
            float4 p1 = P4[(size_t)k4*NN + c1];
            #pragma unroll
            for (int j = 0; j < QB; ++j) {
                float4 qv = *(const float4*)(QR + j*PD + (k4 << 2));  // uniform -> SGPR
                a[j][0] += qv.x*p0.x + qv.y*p0.y + qv.z*p0.z + qv.w*p0.w;
                a[j][1] += qv.x*p1.x + qv.y*p1.y + qv.z*p1.z + qv.w*p1.w;
            }
        }
        const float sc0 = sqf[base + c0], sc1 = sqf[base + c1];
        #pragma unroll
        for (int j = 0; j < QB; ++j) {
            float d0 = fmaxf(sqq[j] + sc0 - 2.f*a[j][0], 0.f);
            float d1 = fmaxf(sqq[j] + sc1 - 2.f*a[j][1], 0.f);
            if (c0 == n0 + j) d0 = 1e30f;   // self
            if (c1 == n0 + j) d1 = 1e30f;
            a[j][0] = d0; a[j][1] = d1;
        }

        if (ch == 0) {
            // t0: smallest bf16 boundary with >=19 of this chunk's 128 d2 strictly below
            #pragma unroll
            for (int j = 0; j < QB; ++j) {
                unsigned lo = 0u, hi = 0x7F80u;
                #pragma unroll 1
                for (int it = 0; it < 16; ++it) {
                    unsigned mid = (lo + hi) >> 1;
                    float fm = __uint_as_float(mid << 16);
                    int cnt = __popcll(__ballot(a[j][0] < fm)) + __popcll(__ballot(a[j][1] < fm));
                    if (cnt >= 19) hi = mid; else lo = mid;
                }
                tv[j] = __uint_as_float(hi << 16);
            }
        }

        // append passers (deterministically within CAP)
        #pragma unroll
        for (int j = 0; j < QB; ++j) {
            if (a[j][0] < tv[j]) {
                int s = atomicAdd(&ccnt[j][w], 1);
                if (s < CAP) {
                    sd16[j][w][s]  = (ushort_t)(__float_as_uint(a[j][0]) >> 16);
                    six16[j][w][s] = (ushort_t)c0;
                }
            }
            if (a[j][1] < tv[j]) {
                int s = atomicAdd(&ccnt[j][w], 1);
                if (s < CAP) {
                    sd16[j][w][s]  = (ushort_t)(__float_as_uint(a[j][1]) >> 16);
                    six16[j][w][s] = (ushort_t)c1;
                }
            }
        }

        // deterministic compact (rare; wave-uniform branch): keep bf16-top-~19, tighten tv
        #pragma unroll
        for (int j = 0; j < QB; ++j) {
            int cnt0 = ccnt[j][w];
            if (cnt0 > CTRIG) {
                if (cnt0 > CAP) cnt0 = CAP;
                ushort_t v0 = (lane       < cnt0) ? sd16[j][w][lane]       : (ushort_t)0xFFFF;
                ushort_t v1 = (64 + lane  < cnt0) ? sd16[j][w][64 + lane]  : (ushort_t)0xFFFF;
                ushort_t v2 = (128 + lane < cnt0) ? sd16[j][w][128 + lane] : (ushort_t)0xFFFF;
                ushort_t i0 = (lane       < cnt0) ? six16[j][w][lane]       : (ushort_t)0;
                ushort_t i1 = (64 + lane  < cnt0) ? six16[j][w][64 + lane]  : (ushort_t)0;
                ushort_t i2 = (128 + lane < cnt0) ? six16[j][w][128 + lane] : (ushort_t)0;
                unsigned lo = 0u, hi = 0x7F80u;
                #pragma unroll 1
                for (int it = 0; it < 16; ++it) {
                    unsigned mid = (lo + hi) >> 1;
                    int cnt = __popcll(__ballot((unsigned)v0 < mid))
                            + __popcll(__ballot((unsigned)v1 < mid))
                            + __popcll(__ballot((unsigned)v2 < mid));
                    if (cnt >= 19) hi = mid; else lo = mid;
                }
                tv[j] = __uint_as_float(hi << 16);
                if (lane == 0) ccnt[j][w] = 0;
                if ((unsigned)v0 < hi) { int s = atomicAdd(&ccnt[j][w], 1); sd16[j][w][s] = v0; six16[j][w][s] = i0; }
                if ((unsigned)v1 < hi) { int s = atomicAdd(&ccnt[j][w], 1); sd16[j][w][s] = v1; six16[j][w][s] = i1; }
                if ((unsigned)v2 < hi) { int s = atomicAdd(&ccnt[j][w], 1); sd16[j][w][s] = v2; six16[j][w][s] = i2; }
            }
        }
    }

    // ---- final compact to rescue list (bf16 20-quantile, keep < t) ----
    if (lane < QB) rcnt[lane][w] = 0;
    #pragma unroll 1
    for (int j = 0; j < QB; ++j) {
        int cnt0 = ccnt[j][w];
        if (cnt0 > CAP) cnt0 = CAP;
        ushort_t v0 = (lane       < cnt0) ? sd16[j][w][lane]       : (ushort_t)0xFFFF;
        ushort_t v1 = (64 + lane  < cnt0) ? sd16[j][w][64 + lane]  : (ushort_t)0xFFFF;
        ushort_t v2 = (128 + lane < cnt0) ? sd16[j][w][128 + lane] : (ushort_t)0xFFFF;
        ushort_t i0 = (lane       < cnt0) ? six16[j][w][lane]       : (ushort_t)0;
        ushort_t i1 = (64 + lane  < cnt0) ? six16[j][w][64 + lane]  : (ushort_t)0;
        ushort_t i2 = (128 + lane < cnt0) ? six16[j][w][128 + lane] : (ushort_t)0;
        unsigned lo = 0u, hi = 0x7F80u;
        #pragma unroll 1
        for (int it = 0; it < 16; ++it) {
            unsigned mid = (lo + hi) >> 1;
            int cnt = __popcll(__ballot((unsigned)v0 < mid))
                    + __popcll(__ballot((unsigned)v1 < mid))
                    + __popcll(__ballot((unsigned)v2 < mid));
            if (cnt >= 20) hi = mid; else lo = mid;
        }
        if ((unsigned)v0 < hi) { int s = atomicAdd(&rcnt[j][w], 1); if (s < RCAP) rlist[j][w][s] = i0; }
        if ((unsigned)v1 < hi) { int s = atomicAdd(&rcnt[j][w], 1); if (s < RCAP) rlist[j][w][s] = i1; }
        if ((unsigned)v2 < hi) { int s = atomicAdd(&rcnt[j][w], 1); if (s < RCAP) rlist[j][w][s] = i2; }
    }
    __syncthreads();   // sd16/six16 dead -> repurpose POOL

    // ---- build qd64 (f64 query rows) + init umb ----
    for (int i = tid; i < QB*PD; i += 256) {
        int q = i >> 6, p = i & 63;
        size_t g = (size_t)(base + n0 + q)*PD + p;
        qd64[q][p] = (double)nph[g] + (double)npl[g];
    }
    for (int i = tid; i < QB*192; i += 256) {
        umbd[i / 192][i % 192] = 1e300;
        umbi[i] = 0x7fffffff;
    }
    __syncthreads();

    // ---- coalesced f64 rescue: 16-lane groups, 4 candidates per iteration ----
    const int lh = lane & 15, g4 = lane >> 4;
    #pragma unroll 1
    for (int q = 0; q < QB; ++q) {
        int cr = rcnt[q][w]; if (cr > RCAP) cr = RCAP;
        const double qd0 = qd64[q][4*lh+0], qd1 = qd64[q][4*lh+1];
        const double qd2 = qd64[q][4*lh+2], qd3 = qd64[q][4*lh+3];
        const double sq_q = sq64[base + n0 + q];
        for (int s0 = 0; s0 < cr; s0 += 4) {
            const int slot = s0 + g4;
            const bool valid = slot < cr;
            const int cand = valid ? (int)rlist[q][w][slot] : 0;
            const float4 h4 = *(const float4*)(nph + (size_t)(base + cand)*PD + 4*lh);
            const float4 l4 = *(const float4*)(npl + (size_t)(base + cand)*PD + 4*lh);
            double acc = qd0*((double)h4.x + (double)l4.x)
                       + qd1*((double)h4.y + (double)l4.y)
                       + qd2*((double)h4.z + (double)l4.z)
                       + qd3*((double)h4.w + (double)l4.w);
            #pragma unroll
            for (int off = 1; off < 16; off <<= 1) acc += __shfl_xor(acc, off);
            if (valid && lh == 0) {
                umbd[q][w*RCAP + slot] = sq_q + sq64[base + cand] - 2.0*acc;
                umbi[q*192 + w*RCAP + slot] = cand;
            }
        }
    }
    __syncthreads();

    // ---- exact f64 top-16 + weights: wave w -> queries 2w, 2w+1 (union <= 192) ----
    #pragma unroll 1
    for (int qi = 0; qi < 2; ++qi) {
        const int q = 2*w + qi;
        double ev0 = umbd[q][lane], ev1 = umbd[q][64 + lane], ev2 = umbd[q][128 + lane];
        int ei0 = umbi[q*192 + lane], ei1 = umbi[q*192 + 64 + lane], ei2 = umbi[q*192 + 128 + lane];
        double wsum = 0.0, mywk = 0.0;
        for (int r = 0; r < KNN; ++r) {
            double bv = ev0; int bi = ei0; int bs = 0;
            if (ev1 < bv || (ev1 == bv && ei1 < bi)) { bv = ev1; bi = ei1; bs = 1; }
            if (ev2 < bv || (ev2 == bv && ei2 < bi)) { bv = ev2; bi = ei2; bs = 2; }
            #pragma unroll
            for (int off = 32; off >= 1; off >>= 1) {
                double ov = __shfl_xor(bv, off);
                int    oi = __shfl_xor(bi, off);
                if (ov < bv || (ov == bv && oi < bi)) { bv = ov; bi = oi; }
            }
            if (bs == 0 && ei0 == bi) ev0 = 1e300;
            if (bs == 1 && ei1 == bi) ev1 = 1e300;
            if (bs == 2 && ei2 == bi) ev2 = 1e300;
            double wk = exp(-0.5 * sqrt(fmax(bv, 1e-12)));
            wsum += wk;
            if (lane == r) mywk = wk;
            if (lane == 0) fin_ix[q*16 + r] = bi;
        }
        if (lane < KNN) fin_w[q*16 + lane] = (float)(mywk / (wsum + 1e-8));
    }
    __syncthreads();

    // ---- context: 8 queries x 512 dims (32 thr/query, 16 dims each) ----
    {
        const int q  = tid >> 5;
        const int e0 = (tid & 31) << 4;
        const float* V = values + (size_t)base * DIMD;
        float acc2[16] = {};
        for (int k = 0; k < KNN; ++k) {
            int   m  = fin_ix[q*16 + k];
            float wg = fin_w[q*16 + k];
            const float4* vr = (const float4*)(V + (size_t)m*DIMD + e0);
            #pragma unroll
            for (int t4 = 0; t4 < 4; ++t4) {
                float4 vv = vr[t4];
                acc2[4*t4+0] += wg*vv.x; acc2[4*t4+1] += wg*vv.y;
                acc2[4*t4+2] += wg*vv.z; acc2[4*t4+3] += wg*vv.w;
            }
        }
        float* crow = ctx + (size_t)(base + n0 + q)*DIMD + e0;
        #pragma unroll
        for (int t4 = 0; t4 < 4; ++t4)
            *(float4*)(crow + 4*t4) = make_float4(acc2[4*t4+0], acc2[4*t4+1], acc2[4*t4+2], acc2[4*t4+3]);
    }
}

extern "C" void kernel_launch(void* const* d_in, const int* in_sizes, int n_in,
                              void* d_out, int out_size, void* d_ws, size_t ws_size,
                              hipStream_t stream)
{
    (void)in_sizes; (void)n_in; (void)out_size; (void)ws_size;
    const float* states    = (const float*)d_in[0];
    const float* positions = (const float*)d_in[1];
    const float* W_flow    = (const float*)d_in[2];
    const float* b_flow    = (const float*)d_in[3];
    const float* W_val     = (const float*)d_in[4];
    const float* b_val     = (const float*)d_in[5];

    float* out_ctx = (float*)d_out;                       // [B,N,DIM]
    float* out_np  = out_ctx + (size_t)NB*NN*DIMD;        // [B,N,PD]
    float* out_fl  = out_np  + (size_t)NB*NN*PD;          // [B,N,PD]

    char* ws = (char*)d_ws;
    float*  values_ws = (float*)ws;                                   // 16,777,216 B
    float*  npos_lo   = (float*)(ws + (size_t)16777216);              //  2,097,152 B
    double* sq64      = (double*)(ws + (size_t)18874368);             //     65,536 B
    float*  sqf       = (float*)(ws + (size_t)18939904);              //     32,768 B
    float*  p4t       = (float*)(ws + (size_t)18972672);              //  2,097,152 B
    // total 21,069,824 B (same footprint as rounds 3-14)

    hipLaunchKernelGGL(prep_kernel, dim3(FLOW_BLOCKS + (DIMD/64)*(MROWS/64)), dim3(256), 0, stream,
                       states, positions, W_flow, b_flow, W_val, b_val,
                       out_np, out_fl, npos_lo, p4t, sq64, sqf, values_ws);
    hipLaunchKernelGGL(dist_kernel, dim3(NB*512), dim3(256), 0, stream,
                       out_np, npos_lo, (const float4*)p4t, sqf, sq64, values_ws, out_ctx);
}

// Round 16
// 383.855 us; speedup vs baseline: 1.8837x; 1.1883x over previous
//
#include <hip/hip_runtime.h>

#define NB 2
#define NN 4096
#define DIMD 512
#define PD 64
#define KNN 16
#define QB 8
#define CAP 192
#define CTRIG 52
#define RCAP 48
#define MROWS (NB*NN)       // 8192
#define FLOW_BLOCKS (MROWS/4)

typedef unsigned short ushort_t;

// ---------------- kernel 1: fused prep = flow (f64, 4-way ILP) + values GEMM ---------------
// (r15's prep verbatim -- measured ~28 us faster than r11's serial-chain flow)
__global__ __launch_bounds__(256)
void prep_kernel(const float* __restrict__ states, const float* __restrict__ positions,
                 const float* __restrict__ W_flow, const float* __restrict__ b_flow,
                 const float* __restrict__ W_val, const float* __restrict__ b_val,
                 float* __restrict__ out_np, float* __restrict__ out_fl,
                 float* __restrict__ npos_lo, float* __restrict__ p4t,
                 double* __restrict__ sq64, float* __restrict__ sqf,
                 float* __restrict__ values_ws)
{
    __shared__ float s_lds[4][DIMD];
    __shared__ float As[16][68];
    __shared__ float Bs[16][68];
    const int t = threadIdx.x;

    if (blockIdx.x < FLOW_BLOCKS) {
        const int row0 = blockIdx.x * 4;
        const float4* src = (const float4*)(states + (size_t)row0 * DIMD);
        float4* dst = (float4*)&s_lds[0][0];
        dst[t] = src[t];
        dst[t + 256] = src[t + 256];
        __syncthreads();
        const int lr = t >> 6;
        const int p  = t & 63;
        const int row = row0 + lr;
        const float4* wr = (const float4*)(W_flow + (size_t)p * DIMD);
        const float4* sr = (const float4*)&s_lds[lr][0];
        // 4 independent f64 partials (break the 512-deep dependent FMA chain)
        double a0 = 0.0, a1 = 0.0, a2 = 0.0, a3 = 0.0;
        #pragma unroll 8
        for (int d4 = 0; d4 < DIMD/4; ++d4) {
            float4 w4 = wr[d4];
            float4 s4 = sr[d4];
            a0 += (double)s4.x * (double)w4.x;
            a1 += (double)s4.y * (double)w4.y;
            a2 += (double)s4.z * (double)w4.z;
            a3 += (double)s4.w * (double)w4.w;
        }
        double acc = ((a0 + a1) + (a2 + a3)) + (double)b_flow[p];
        const size_t g = (size_t)row * PD + p;
        double np_ = (double)positions[g] + 0.1 * acc;
        float hi = (float)np_;
        float lo = (float)(np_ - (double)hi);
        out_fl[g]   = (float)acc;
        out_np[g]   = hi;
        npos_lo[g]  = lo;
        const int bb = row >> 12, n = row & (NN - 1);
        p4t[(((size_t)bb*16 + (p >> 2))*NN + n)*4 + (p & 3)] = hi;
        double s2 = np_ * np_;
        #pragma unroll
        for (int off = 32; off >= 1; off >>= 1) s2 += __shfl_xor(s2, off);
        if (p == 0) { sq64[row] = s2; sqf[row] = (float)s2; }
    } else {
        const int idx = blockIdx.x - FLOW_BLOCKS;
        const int bn = idx & 7, bm = idx >> 3;
        const int lr  = t >> 2;
        const int lc4 = (t & 3) << 2;
        const int cr = (t >> 4) << 2;
        const int cc = (t & 15) << 2;
        float acc[4][4] = {};
        for (int k0 = 0; k0 < DIMD; k0 += 16) {
            float4 av = *(const float4*)(states + (size_t)(bm*64 + lr)*DIMD + k0 + lc4);
            float4 wv = *(const float4*)(W_val  + (size_t)(bn*64 + lr)*DIMD + k0 + lc4);
            __syncthreads();
            As[lc4+0][lr] = av.x; As[lc4+1][lr] = av.y; As[lc4+2][lr] = av.z; As[lc4+3][lr] = av.w;
            Bs[lc4+0][lr] = wv.x; Bs[lc4+1][lr] = wv.y; Bs[lc4+2][lr] = wv.z; Bs[lc4+3][lr] = wv.w;
            __syncthreads();
            #pragma unroll
            for (int kk = 0; kk < 16; ++kk) {
                float4 a  = *(const float4*)&As[kk][cr];
                float4 b4 = *(const float4*)&Bs[kk][cc];
                acc[0][0] += a.x*b4.x; acc[0][1] += a.x*b4.y; acc[0][2] += a.x*b4.z; acc[0][3] += a.x*b4.w;
                acc[1][0] += a.y*b4.x; acc[1][1] += a.y*b4.y; acc[1][2] += a.y*b4.z; acc[1][3] += a.y*b4.w;
                acc[2][0] += a.z*b4.x; acc[2][1] += a.z*b4.y; acc[2][2] += a.z*b4.z; acc[2][3] += a.z*b4.w;
                acc[3][0] += a.w*b4.x; acc[3][1] += a.w*b4.y; acc[3][2] += a.w*b4.z; acc[3][3] += a.w*b4.w;
            }
        }
        const int colb = bn*64 + cc;
        float4 bb = *(const float4*)(b_val + colb);
        #pragma unroll
        for (int i = 0; i < 4; ++i) {
            float4 o;
            o.x = acc[i][0] + bb.x;
            o.y = acc[i][1] + bb.y;
            o.z = acc[i][2] + bb.z;
            o.w = acc[i][3] + bb.w;
            *(float4*)(values_ws + (size_t)(bm*64 + cr + i)*DIMD + colb) = o;
        }
    }
}

// ---------------- kernel 2: 8q/block dedup scan + f64 rescue + context (r11 VERBATIM) ------
// r11 measured: dist 240 us, VALUBusy 57%, occupancy 38%, no spill. qstage LDS broadcast
// reads restored (r15's global-uniform read emitted per-lane VMEM, +90 us).
__global__ __launch_bounds__(256, 4)
void dist_kernel(const float* __restrict__ nph, const float* __restrict__ npl,
                 const float4* __restrict__ p4t, const float* __restrict__ sqf,
                 const double* __restrict__ sq64, const float* __restrict__ values,
                 float* __restrict__ ctx)
{
    __shared__ __align__(16) unsigned char POOL[24576];
    __shared__ float    qstage[QB][68];
    __shared__ ushort_t rlist[QB][4][RCAP];
    __shared__ int      ccnt[QB][4];
    __shared__ int      rcnt[QB][4];

    // phase 1 aliases
    ushort_t (*sd16)[4][CAP]  = (ushort_t(*)[4][CAP])POOL;               // 12288
    ushort_t (*six16)[4][CAP] = (ushort_t(*)[4][CAP])(POOL + 12288);     // 12288
    // phase 2 aliases
    double (*umbd)[192] = (double(*)[192])POOL;                          // 12288
    int*    umbi        = (int*)(POOL + 12288);                          //  6144
    double (*qd64)[66]  = (double(*)[66])(POOL + 18432);                 //  4224
    int*    fin_ix      = (int*)(POOL + 22656);                          //   512
    float*  fin_w       = (float*)(POOL + 23168);                        //   512

    const int tid  = threadIdx.x;
    const int w    = tid >> 6;        // quarter id
    const int lane = tid & 63;
    const int b    = blockIdx.x >> 9;
    const int n0   = (blockIdx.x & 511) << 3;
    const int base = b * NN;

    if (tid < 32) ccnt[tid >> 2][tid & 3] = 0;
    if (tid < 128) {
        int row = tid >> 4, c4 = (tid & 15) << 2;
        *(float4*)&qstage[row][c4] = *(const float4*)(nph + (size_t)(base + n0 + row)*PD + c4);
    }
    __syncthreads();

    float sqq[QB], tv[QB];
    #pragma unroll
    for (int j = 0; j < QB; ++j) { sqq[j] = sqf[base + n0 + j]; tv[j] = 1e30f; }

    const float4* P4 = p4t + (size_t)b * 16 * NN;
    const int qbase = w << 10;

    // ---- scan: 8 chunks of 128 cands per quarter ----
    for (int ch = 0; ch < 8; ++ch) {
        const int cbase = qbase + (ch << 7);
        const int c0 = cbase + lane, c1 = c0 + 64;
        float a[QB][2];
        #pragma unroll
        for (int j = 0; j < QB; ++j) { a[j][0] = 0.f; a[j][1] = 0.f; }
        #pragma unroll
        for (int k4 = 0; k4 < 16; ++k4) {
            float4 p0 = P4[(size_t)k4*NN + c0];
            float4 p1 = P4[(size_t)k4*NN + c1];
            #pragma unroll
            for (int j = 0; j < QB; ++j) {
                float4 qv = *(const float4*)&qstage[j][k4 << 2];
                a[j][0] += qv.x*p0.x + qv.y*p0.y + qv.z*p0.z + qv.w*p0.w;
                a[j][1] += qv.x*p1.x + qv.y*p1.y + qv.z*p1.z + qv.w*p1.w;
            }
        }
        const float sc0 = sqf[base + c0], sc1 = sqf[base + c1];
        #pragma unroll
        for (int j = 0; j < QB; ++j) {
            float d0 = fmaxf(sqq[j] + sc0 - 2.f*a[j][0], 0.f);
            float d1 = fmaxf(sqq[j] + sc1 - 2.f*a[j][1], 0.f);
            if (c0 == n0 + j) d0 = 1e30f;   // self
            if (c1 == n0 + j) d1 = 1e30f;
            a[j][0] = d0; a[j][1] = d1;
        }

        if (ch == 0) {
            // t0: smallest bf16 boundary with >=19 of this chunk's 128 d2 strictly below
            #pragma unroll
            for (int j = 0; j < QB; ++j) {
                unsigned lo = 0u, hi = 0x7F80u;
                #pragma unroll 1
                for (int it = 0; it < 16; ++it) {
                    unsigned mid = (lo + hi) >> 1;
                    float fm = __uint_as_float(mid << 16);
                    int cnt = __popcll(__ballot(a[j][0] < fm)) + __popcll(__ballot(a[j][1] < fm));
                    if (cnt >= 19) hi = mid; else lo = mid;
                }
                tv[j] = __uint_as_float(hi << 16);
            }
        }

        // append passers (deterministically within CAP)
        #pragma unroll
        for (int j = 0; j < QB; ++j) {
            if (a[j][0] < tv[j]) {
                int s = atomicAdd(&ccnt[j][w], 1);
                if (s < CAP) {
                    sd16[j][w][s]  = (ushort_t)(__float_as_uint(a[j][0]) >> 16);
                    six16[j][w][s] = (ushort_t)c0;
                }
            }
            if (a[j][1] < tv[j]) {
                int s = atomicAdd(&ccnt[j][w], 1);
                if (s < CAP) {
                    sd16[j][w][s]  = (ushort_t)(__float_as_uint(a[j][1]) >> 16);
                    six16[j][w][s] = (ushort_t)c1;
                }
            }
        }

        // deterministic compact (rare; wave-uniform branch): keep bf16-top-~19, tighten tv
        #pragma unroll
        for (int j = 0; j < QB; ++j) {
            int cnt0 = ccnt[j][w];
            if (cnt0 > CTRIG) {
                if (cnt0 > CAP) cnt0 = CAP;
                ushort_t v0 = (lane       < cnt0) ? sd16[j][w][lane]       : (ushort_t)0xFFFF;
                ushort_t v1 = (64 + lane  < cnt0) ? sd16[j][w][64 + lane]  : (ushort_t)0xFFFF;
                ushort_t v2 = (128 + lane < cnt0) ? sd16[j][w][128 + lane] : (ushort_t)0xFFFF;
                ushort_t i0 = (lane       < cnt0) ? six16[j][w][lane]       : (ushort_t)0;
                ushort_t i1 = (64 + lane  < cnt0) ? six16[j][w][64 + lane]  : (ushort_t)0;
                ushort_t i2 = (128 + lane < cnt0) ? six16[j][w][128 + lane] : (ushort_t)0;
                unsigned lo = 0u, hi = 0x7F80u;
                #pragma unroll 1
                for (int it = 0; it < 16; ++it) {
                    unsigned mid = (lo + hi) >> 1;
                    int cnt = __popcll(__ballot((unsigned)v0 < mid))
                            + __popcll(__ballot((unsigned)v1 < mid))
                            + __popcll(__ballot((unsigned)v2 < mid));
                    if (cnt >= 19) hi = mid; else lo = mid;
                }
                tv[j] = __uint_as_float(hi << 16);
                if (lane == 0) ccnt[j][w] = 0;
                if ((unsigned)v0 < hi) { int s = atomicAdd(&ccnt[j][w], 1); sd16[j][w][s] = v0; six16[j][w][s] = i0; }
                if ((unsigned)v1 < hi) { int s = atomicAdd(&ccnt[j][w], 1); sd16[j][w][s] = v1; six16[j][w][s] = i1; }
                if ((unsigned)v2 < hi) { int s = atomicAdd(&ccnt[j][w], 1); sd16[j][w][s] = v2; six16[j][w][s] = i2; }
            }
        }
    }

    // ---- final compact to rescue list (bf16 20-quantile, keep < t) ----
    if (lane < QB) rcnt[lane][w] = 0;
    #pragma unroll 1
    for (int j = 0; j < QB; ++j) {
        int cnt0 = ccnt[j][w];
        if (cnt0 > CAP) cnt0 = CAP;
        ushort_t v0 = (lane       < cnt0) ? sd16[j][w][lane]       : (ushort_t)0xFFFF;
        ushort_t v1 = (64 + lane  < cnt0) ? sd16[j][w][64 + lane]  : (ushort_t)0xFFFF;
        ushort_t v2 = (128 + lane < cnt0) ? sd16[j][w][128 + lane] : (ushort_t)0xFFFF;
        ushort_t i0 = (lane       < cnt0) ? six16[j][w][lane]       : (ushort_t)0;
        ushort_t i1 = (64 + lane  < cnt0) ? six16[j][w][64 + lane]  : (ushort_t)0;
        ushort_t i2 = (128 + lane < cnt0) ? six16[j][w][128 + lane] : (ushort_t)0;
        unsigned lo = 0u, hi = 0x7F80u;
        #pragma unroll 1
        for (int it = 0; it < 16; ++it) {
            unsigned mid = (lo + hi) >> 1;
            int cnt = __popcll(__ballot((unsigned)v0 < mid))
                    + __popcll(__ballot((unsigned)v1 < mid))
                    + __popcll(__ballot((unsigned)v2 < mid));
            if (cnt >= 20) hi = mid; else lo = mid;
        }
        if ((unsigned)v0 < hi) { int s = atomicAdd(&rcnt[j][w], 1); if (s < RCAP) rlist[j][w][s] = i0; }
        if ((unsigned)v1 < hi) { int s = atomicAdd(&rcnt[j][w], 1); if (s < RCAP) rlist[j][w][s] = i1; }
        if ((unsigned)v2 < hi) { int s = atomicAdd(&rcnt[j][w], 1); if (s < RCAP) rlist[j][w][s] = i2; }
    }
    __syncthreads();   // sd16/six16 dead -> repurpose POOL

    // ---- build qd64 (f64 query rows) + init umb ----
    for (int i = tid; i < QB*PD; i += 256) {
        int q = i >> 6, p = i & 63;
        size_t g = (size_t)(base + n0 + q)*PD + p;
        qd64[q][p] = (double)nph[g] + (double)npl[g];
    }
    for (int i = tid; i < QB*192; i += 256) {
        umbd[i / 192][i % 192] = 1e300;
        umbi[i] = 0x7fffffff;
    }
    __syncthreads();

    // ---- coalesced f64 rescue: 16-lane groups, 4 candidates per iteration ----
    const int lh = lane & 15, g4 = lane >> 4;
    #pragma unroll 1
    for (int q = 0; q < QB; ++q) {
        int cr = rcnt[q][w]; if (cr > RCAP) cr = RCAP;
        const double qd0 = qd64[q][4*lh+0], qd1 = qd64[q][4*lh+1];
        const double qd2 = qd64[q][4*lh+2], qd3 = qd64[q][4*lh+3];
        const double sq_q = sq64[base + n0 + q];
        for (int s0 = 0; s0 < cr; s0 += 4) {
            const int slot = s0 + g4;
            const bool valid = slot < cr;
            const int cand = valid ? (int)rlist[q][w][slot] : 0;
            const float4 h4 = *(const float4*)(nph + (size_t)(base + cand)*PD + 4*lh);
            const float4 l4 = *(const float4*)(npl + (size_t)(base + cand)*PD + 4*lh);
            double acc = qd0*((double)h4.x + (double)l4.x)
                       + qd1*((double)h4.y + (double)l4.y)
                       + qd2*((double)h4.z + (double)l4.z)
                       + qd3*((double)h4.w + (double)l4.w);
            #pragma unroll
            for (int off = 1; off < 16; off <<= 1) acc += __shfl_xor(acc, off);
            if (valid && lh == 0) {
                umbd[q][w*RCAP + slot] = sq_q + sq64[base + cand] - 2.0*acc;
                umbi[q*192 + w*RCAP + slot] = cand;
            }
        }
    }
    __syncthreads();

    // ---- exact f64 top-16 + weights: wave w -> queries 2w, 2w+1 (union <= 192) ----
    #pragma unroll 1
    for (int qi = 0; qi < 2; ++qi) {
        const int q = 2*w + qi;
        double ev0 = umbd[q][lane], ev1 = umbd[q][64 + lane], ev2 = umbd[q][128 + lane];
        int ei0 = umbi[q*192 + lane], ei1 = umbi[q*192 + 64 + lane], ei2 = umbi[q*192 + 128 + lane];
        double wsum = 0.0, mywk = 0.0;
        for (int r = 0; r < KNN; ++r) {
            double bv = ev0; int bi = ei0; int bs = 0;
            if (ev1 < bv || (ev1 == bv && ei1 < bi)) { bv = ev1; bi = ei1; bs = 1; }
            if (ev2 < bv || (ev2 == bv && ei2 < bi)) { bv = ev2; bi = ei2; bs = 2; }
            #pragma unroll
            for (int off = 32; off >= 1; off >>= 1) {
                double ov = __shfl_xor(bv, off);
                int    oi = __shfl_xor(bi, off);
                if (ov < bv || (ov == bv && oi < bi)) { bv = ov; bi = oi; }
            }
            if (bs == 0 && ei0 == bi) ev0 = 1e300;
            if (bs == 1 && ei1 == bi) ev1 = 1e300;
            if (bs == 2 && ei2 == bi) ev2 = 1e300;
            double wk = exp(-0.5 * sqrt(fmax(bv, 1e-12)));
            wsum += wk;
            if (lane == r) mywk = wk;
            if (lane == 0) fin_ix[q*16 + r] = bi;
        }
        if (lane < KNN) fin_w[q*16 + lane] = (float)(mywk / (wsum + 1e-8));
    }
    __syncthreads();

    // ---- context: 8 queries x 512 dims (32 thr/query, 16 dims each) ----
    {
        const int q  = tid >> 5;
        const int e0 = (tid & 31) << 4;
        const float* V = values + (size_t)base * DIMD;
        float acc2[16] = {};
        for (int k = 0; k < KNN; ++k) {
            int   m  = fin_ix[q*16 + k];
            float wg = fin_w[q*16 + k];
            const float4* vr = (const float4*)(V + (size_t)m*DIMD + e0);
            #pragma unroll
            for (int t4 = 0; t4 < 4; ++t4) {
                float4 vv = vr[t4];
                acc2[4*t4+0] += wg*vv.x; acc2[4*t4+1] += wg*vv.y;
                acc2[4*t4+2] += wg*vv.z; acc2[4*t4+3] += wg*vv.w;
            }
        }
        float* crow = ctx + (size_t)(base + n0 + q)*DIMD + e0;
        #pragma unroll
        for (int t4 = 0; t4 < 4; ++t4)
            *(float4*)(crow + 4*t4) = make_float4(acc2[4*t4+0], acc2[4*t4+1], acc2[4*t4+2], acc2[4*t4+3]);
    }
}

extern "C" void kernel_launch(void* const* d_in, const int* in_sizes, int n_in,
                              void* d_out, int out_size, void* d_ws, size_t ws_size,
                              hipStream_t stream)
{
    (void)in_sizes; (void)n_in; (void)out_size; (void)ws_size;
    const float* states    = (const float*)d_in[0];
    const float* positions = (const float*)d_in[1];
    const float* W_flow    = (const float*)d_in[2];
    const float* b_flow    = (const float*)d_in[3];
    const float* W_val     = (const float*)d_in[4];
    const float* b_val     = (const float*)d_in[5];

    float* out_ctx = (float*)d_out;                       // [B,N,DIM]
    float* out_np  = out_ctx + (size_t)NB*NN*DIMD;        // [B,N,PD]
    float* out_fl  = out_np  + (size_t)NB*NN*PD;          // [B,N,PD]

    char* ws = (char*)d_ws;
    float*  values_ws = (float*)ws;                                   // 16,777,216 B
    float*  npos_lo   = (float*)(ws + (size_t)16777216);              //  2,097,152 B
    double* sq64      = (double*)(ws + (size_t)18874368);             //     65,536 B
    float*  sqf       = (float*)(ws + (size_t)18939904);              //     32,768 B
    float*  p4t       = (float*)(ws + (size_t)18972672);              //  2,097,152 B
    // total 21,069,824 B (same footprint as rounds 3-15)

    hipLaunchKernelGGL(prep_kernel, dim3(FLOW_BLOCKS + (DIMD/64)*(MROWS/64)), dim3(256), 0, stream,
                       states, positions, W_flow, b_flow, W_val, b_val,
                       out_np, out_fl, npos_lo, p4t, sq64, sqf, values_ws);
    hipLaunchKernelGGL(dist_kernel, dim3(NB*512), dim3(256), 0, stream,
                       out_np, npos_lo, (const float4*)p4t, sqf, sq64, values_ws, out_ctx);
}